// Round 1
// baseline (746.983 us; speedup 1.0000x reference)
//
#include <hip/hip_runtime.h>

typedef __attribute__((ext_vector_type(4))) float f32x4;
typedef __attribute__((ext_vector_type(8))) __bf16 bf16x8;
typedef unsigned short u16;

#define GAS(p) ((const __attribute__((address_space(1))) void*)(p))
#define LAS(p) ((__attribute__((address_space(3))) void*)(p))

__device__ __forceinline__ u16 f32_to_bf16(float f) {
  unsigned u = __builtin_bit_cast(unsigned, f);
  u += 0x7FFFu + ((u >> 16) & 1u);
  return (u16)(u >> 16);
}

// ---------------- elementwise f32 -> bf16 ----------------
__global__ __launch_bounds__(256) void k_convert(const float* __restrict__ X,
                                                 u16* __restrict__ Y, int n4) {
  int i = blockIdx.x * 256 + threadIdx.x;
  if (i >= n4) return;
  float4 v = ((const float4*)X)[i];
  ushort4 r;
  r.x = f32_to_bf16(v.x); r.y = f32_to_bf16(v.y);
  r.z = f32_to_bf16(v.z); r.w = f32_to_bf16(v.w);
  ((ushort4*)Y)[i] = r;
}

// ---------------- W [K][N] f32 -> WT [N][K] bf16 ----------------
__global__ __launch_bounds__(256) void k_transpose_w(const float* __restrict__ W,
                                                     u16* __restrict__ WT,
                                                     int K, int N) {
  __shared__ float tile[32][33];
  int n0 = blockIdx.x * 32, k0 = blockIdx.y * 32;
  int tx = threadIdx.x & 31, ty = threadIdx.x >> 5;
#pragma unroll
  for (int r = 0; r < 4; ++r)
    tile[ty + r * 8][tx] = W[(long)(k0 + ty + r * 8) * N + n0 + tx];
  __syncthreads();
#pragma unroll
  for (int r = 0; r < 4; ++r)
    WT[(long)(n0 + ty + r * 8) * K + k0 + tx] = f32_to_bf16(tile[tx][ty + r * 8]);
}

// ---------------- V [BH][S][128] bf16 -> VT [BH][128][S] bf16 ----------------
__global__ __launch_bounds__(256) void k_transpose_v(const u16* __restrict__ V,
                                                     u16* __restrict__ VT) {
  __shared__ u16 tile[32][34];
  int s0 = blockIdx.x * 32, d0 = blockIdx.y * 32, bh = blockIdx.z;
  int tx = threadIdx.x & 31, ty = threadIdx.x >> 5;
  const u16* Vb = V + (long)bh * 2048 * 128;
  u16* VTb = VT + (long)bh * 128 * 2048;
#pragma unroll
  for (int r = 0; r < 4; ++r)
    tile[ty + r * 8][tx] = Vb[(long)(s0 + ty + r * 8) * 128 + d0 + tx];
  __syncthreads();
#pragma unroll
  for (int r = 0; r < 4; ++r)
    VTb[(long)(d0 + ty + r * 8) * 2048 + s0 + tx] = tile[tx][ty + r * 8];
}

// ---------------- m97-structure bf16 GEMM, 128x128 tile, BK=32 ----------------
// A [M][K] bf16 row-major, BT [N][K] bf16 (B transposed), acc fp32.
// EPI==0: scatter Q/K/V bf16 per-head (+bias). EPI==1: fp32 out = acc + bias.
template <int EPI>
__global__ __launch_bounds__(256) void k_gemm(
    const u16* __restrict__ A, const u16* __restrict__ BT,
    const float* __restrict__ bias,
    u16* __restrict__ Qo, u16* __restrict__ Ko, u16* __restrict__ Vo,
    float* __restrict__ Cout, int M, int N, int K) {
  __shared__ alignas(16) u16 As[128 * 32];
  __shared__ alignas(16) u16 Bs[128 * 32];
  const int t = threadIdx.x;
  const int wave = t >> 6, lane = t & 63;
  const int wr = wave >> 1, wc = wave & 1;
  const int l15 = lane & 15, l4 = lane >> 4;
  const int brow = blockIdx.x * 128, bcol = blockIdx.y * 128;

  const f32x4 fzero = {0.f, 0.f, 0.f, 0.f};
  f32x4 acc[4][4];
#pragma unroll
  for (int m = 0; m < 4; ++m)
#pragma unroll
    for (int n = 0; n < 4; ++n) acc[m][n] = fzero;

  // staging: 512 chunks of 16B per tile; chunk c -> row c>>2, col-chunk c&3
  const int c0 = wave * 64 + lane;
  const int c1 = 256 + c0;
  const u16* ga0 = A + (long)(brow + (c0 >> 2)) * K + (c0 & 3) * 8;
  const u16* ga1 = A + (long)(brow + (c1 >> 2)) * K + (c1 & 3) * 8;
  const u16* gb0 = BT + (long)(bcol + (c0 >> 2)) * K + (c0 & 3) * 8;
  const u16* gb1 = BT + (long)(bcol + (c1 >> 2)) * K + (c1 & 3) * 8;
  char* lA0 = (char*)As + (wave * 64) * 16;
  char* lA1 = (char*)As + (256 + wave * 64) * 16;
  char* lB0 = (char*)Bs + (wave * 64) * 16;
  char* lB1 = (char*)Bs + (256 + wave * 64) * 16;

  for (int k0 = 0; k0 < K; k0 += 32) {
    __builtin_amdgcn_global_load_lds(GAS(ga0 + k0), LAS(lA0), 16, 0, 0);
    __builtin_amdgcn_global_load_lds(GAS(ga1 + k0), LAS(lA1), 16, 0, 0);
    __builtin_amdgcn_global_load_lds(GAS(gb0 + k0), LAS(lB0), 16, 0, 0);
    __builtin_amdgcn_global_load_lds(GAS(gb1 + k0), LAS(lB1), 16, 0, 0);
    __syncthreads();
    bf16x8 af[4], bf[4];
#pragma unroll
    for (int m = 0; m < 4; ++m)
      af[m] = *(const bf16x8*)(As + (wr * 64 + m * 16 + l15) * 32 + l4 * 8);
#pragma unroll
    for (int n = 0; n < 4; ++n)
      bf[n] = *(const bf16x8*)(Bs + (wc * 64 + n * 16 + l15) * 32 + l4 * 8);
#pragma unroll
    for (int m = 0; m < 4; ++m)
#pragma unroll
      for (int n = 0; n < 4; ++n)
        acc[m][n] =
            __builtin_amdgcn_mfma_f32_16x16x32_bf16(af[m], bf[n], acc[m][n], 0, 0, 0);
    __syncthreads();
  }

  if (EPI == 0) {
    // cols [bcol, bcol+128) lie fully inside one of Q/K/V (2048 each)
    const int which = bcol >> 11;
    u16* dst = (which == 0) ? Qo : (which == 1) ? Ko : Vo;
    const int cbase = bcol & 2047;
#pragma unroll
    for (int n = 0; n < 4; ++n) {
      int col = cbase + wc * 64 + n * 16 + l15;
      int h = col >> 7, d = col & 127;
      float bv = bias[bcol + wc * 64 + n * 16 + l15];
#pragma unroll
      for (int m = 0; m < 4; ++m) {
#pragma unroll
        for (int r = 0; r < 4; ++r) {
          int row = brow + wr * 64 + m * 16 + l4 * 4 + r;  // b*2048 + s
          int b = row >> 11, s = row & 2047;
          dst[(((long)(b * 16 + h)) * 2048 + s) * 128 + d] =
              f32_to_bf16(acc[m][n][r] + bv);
        }
      }
    }
  } else {
#pragma unroll
    for (int m = 0; m < 4; ++m) {
#pragma unroll
      for (int r = 0; r < 4; ++r) {
        int row = brow + wr * 64 + m * 16 + l4 * 4 + r;
#pragma unroll
        for (int n = 0; n < 4; ++n) {
          int col = bcol + wc * 64 + n * 16 + l15;
          Cout[(long)row * N + col] = acc[m][n][r] + bias[col];
        }
      }
    }
  }
}

// ---------------- flash attention with ALiBi, causal ----------------
// Q,K [BH][S][128] bf16; VT [BH][128][S] bf16; Oa [B*S][2048] bf16.
// Block: 4 waves x 16 q-rows (QTILE=64), KV tiles of 64. grid (32 qt, 32 bh).
__global__ __launch_bounds__(256) void k_attn(const u16* __restrict__ Q,
                                              const u16* __restrict__ Kp,
                                              const u16* __restrict__ VT,
                                              u16* __restrict__ Oa) {
  __shared__ alignas(16) u16 Pl[4 * 16 * 64];  // per-wave 16x64 P, XOR-swizzled
  const int qt = (int)gridDim.x - 1 - (int)blockIdx.x;  // heavy blocks first
  const int bh = blockIdx.y;
  const int b = bh >> 4, h = bh & 15;
  const int wave = threadIdx.x >> 6, lane = threadIdx.x & 63;
  const int l15 = lane & 15, l4 = lane >> 4;
  const float scale = 0.08838834764831845f;  // 1/sqrt(128)
  const float slope = exp2f(-0.5f * (float)h);

  const int q0 = qt * 64 + wave * 16;  // this wave's q block
  const u16* Qb = Q + ((long)bh * 2048 + q0 + l15) * 128;
  bf16x8 qf[4];
#pragma unroll
  for (int kk = 0; kk < 4; ++kk) qf[kk] = *(const bf16x8*)(Qb + kk * 32 + l4 * 8);

  const u16* Kb = Kp + (long)bh * 2048 * 128;
  const u16* Vb = VT + (long)bh * 128 * 2048;
  u16* Pw = Pl + wave * 16 * 64;

  float mrun[4], lrun[4];
  f32x4 O[8];
  const f32x4 fzero = {0.f, 0.f, 0.f, 0.f};
#pragma unroll
  for (int r = 0; r < 4; ++r) { mrun[r] = -1e30f; lrun[r] = 0.f; }
#pragma unroll
  for (int nb = 0; nb < 8; ++nb) O[nb] = fzero;

  const int irow = q0 + l4 * 4;  // this lane's 4 rows are irow+reg
  for (int jt = 0; jt <= qt; ++jt) {
    const int j0 = jt * 64;
    float sv[4][4];
#pragma unroll
    for (int cb = 0; cb < 4; ++cb) {
      f32x4 sa = fzero;
      const u16* kp = Kb + (long)(j0 + cb * 16 + l15) * 128 + l4 * 8;
#pragma unroll
      for (int kk = 0; kk < 4; ++kk) {
        bf16x8 kf = *(const bf16x8*)(kp + kk * 32);
        sa = __builtin_amdgcn_mfma_f32_16x16x32_bf16(qf[kk], kf, sa, 0, 0, 0);
      }
      const int j = j0 + cb * 16 + l15;
#pragma unroll
      for (int r = 0; r < 4; ++r) {
        int i = irow + r;
        float s = sa[r] * scale - slope * (float)(i - j);
        sv[cb][r] = (j <= i) ? s : -1e30f;
      }
    }
    // row max over the 64 cols (16 lanes per row-group share a row set)
    float pm[4];
#pragma unroll
    for (int r = 0; r < 4; ++r) {
      float v = fmaxf(fmaxf(sv[0][r], sv[1][r]), fmaxf(sv[2][r], sv[3][r]));
      v = fmaxf(v, __shfl_xor(v, 1));
      v = fmaxf(v, __shfl_xor(v, 2));
      v = fmaxf(v, __shfl_xor(v, 4));
      v = fmaxf(v, __shfl_xor(v, 8));
      pm[r] = v;
    }
    float alpha[4], rs[4];
#pragma unroll
    for (int r = 0; r < 4; ++r) {
      float mnew = fmaxf(mrun[r], pm[r]);
      alpha[r] = __expf(mrun[r] - mnew);
      mrun[r] = mnew;
      rs[r] = 0.f;
    }
    // P = exp(S - m), write bf16 to swizzled LDS
#pragma unroll
    for (int cb = 0; cb < 4; ++cb) {
#pragma unroll
      for (int r = 0; r < 4; ++r) {
        float p = __expf(sv[cb][r] - mrun[r]);
        rs[r] += p;
        int rloc = l4 * 4 + r;
        int cbyte = (cb * 16 + l15) * 2;
        *(u16*)((char*)Pw + rloc * 128 + (cbyte ^ ((rloc & 7) << 4))) =
            f32_to_bf16(p);
      }
    }
#pragma unroll
    for (int r = 0; r < 4; ++r) {
      float v = rs[r];
      v += __shfl_xor(v, 1);
      v += __shfl_xor(v, 2);
      v += __shfl_xor(v, 4);
      v += __shfl_xor(v, 8);
      lrun[r] = lrun[r] * alpha[r] + v;
    }
    __syncthreads();
    bf16x8 pf0 = *(const bf16x8*)((char*)Pw + l15 * 128 +
                                  ((l4 * 16) ^ ((l15 & 7) << 4)));
    bf16x8 pf1 = *(const bf16x8*)((char*)Pw + l15 * 128 +
                                  ((64 + l4 * 16) ^ ((l15 & 7) << 4)));
#pragma unroll
    for (int nb = 0; nb < 8; ++nb)
#pragma unroll
      for (int r = 0; r < 4; ++r) O[nb][r] *= alpha[r];
#pragma unroll
    for (int nb = 0; nb < 8; ++nb) {
      const u16* vp = Vb + (long)(nb * 16 + l15) * 2048 + j0 + l4 * 8;
      bf16x8 v0 = *(const bf16x8*)(vp);
      bf16x8 v1 = *(const bf16x8*)(vp + 32);
      O[nb] = __builtin_amdgcn_mfma_f32_16x16x32_bf16(pf0, v0, O[nb], 0, 0, 0);
      O[nb] = __builtin_amdgcn_mfma_f32_16x16x32_bf16(pf1, v1, O[nb], 0, 0, 0);
    }
    __syncthreads();
  }
#pragma unroll
  for (int r = 0; r < 4; ++r) {
    float inv = 1.f / lrun[r];
    int i = irow + r;
    u16* op = Oa + ((long)b * 2048 + i) * 2048 + h * 128;
#pragma unroll
    for (int nb = 0; nb < 8; ++nb) op[nb * 16 + l15] = f32_to_bf16(O[nb][r] * inv);
  }
}

extern "C" void kernel_launch(void* const* d_in, const int* in_sizes, int n_in,
                              void* d_out, int out_size, void* d_ws, size_t ws_size,
                              hipStream_t stream) {
  const float* x = (const float*)d_in[0];
  const float* Wqkv = (const float*)d_in[1];
  const float* bqkv = (const float*)d_in[2];
  const float* Wo = (const float*)d_in[3];
  const float* bo = (const float*)d_in[4];
  float* out = (float*)d_out;

  // workspace layout (bytes), peak 100.7 MB:
  // [0, 16M)      xb (bf16 x), later reused as VT
  // [16M, 41M)    WqkvT, later reused as attn_out (bf16 [B*S][2048])
  // [41M, 50M)    WoT
  // [50M, 67M)    Q   [B,H,S,128] bf16
  // [67M, 84M)    K
  // [84M, 100.7M) V
  char* ws = (char*)d_ws;
  u16* xb = (u16*)(ws);
  u16* VTb = (u16*)(ws);  // aliases xb (xb dead after GEMM1)
  u16* WqkvT = (u16*)(ws + 16777216);
  u16* attn_out = (u16*)(ws + 16777216);  // aliases WqkvT (dead after GEMM1)
  u16* WoT = (u16*)(ws + 16777216 + 25165824);
  u16* Qb = (u16*)(ws + 50331648);
  u16* Kb = (u16*)(ws + 67108864);
  u16* Vb = (u16*)(ws + 83886080);

  // 1. x -> bf16
  k_convert<<<8192, 256, 0, stream>>>(x, xb, 8388608 / 4);
  // 2. weight transposes (f32 -> bf16 [N][K])
  k_transpose_w<<<dim3(192, 64), 256, 0, stream>>>(Wqkv, WqkvT, 2048, 6144);
  k_transpose_w<<<dim3(64, 64), 256, 0, stream>>>(Wo, WoT, 2048, 2048);
  // 3. QKV projection
  k_gemm<0><<<dim3(32, 48), 256, 0, stream>>>(xb, WqkvT, bqkv, Qb, Kb, Vb,
                                              nullptr, 4096, 6144, 2048);
  // 4. V -> VT (into xb region, now dead)
  k_transpose_v<<<dim3(64, 4, 32), 256, 0, stream>>>(Vb, VTb);
  // 5. attention (writes attn_out into WqkvT region, now dead)
  k_attn<<<dim3(32, 32), 256, 0, stream>>>(Qb, Kb, VTb, attn_out);
  // 6. output projection
  k_gemm<1><<<dim3(32, 16), 256, 0, stream>>>(attn_out, WoT, bo, nullptr,
                                              nullptr, nullptr, out, 4096, 2048,
                                              2048);
}

// Round 2
// 505.581 us; speedup vs baseline: 1.4775x; 1.4775x over previous
//
#include <hip/hip_runtime.h>

typedef __attribute__((ext_vector_type(4))) float f32x4;
typedef __attribute__((ext_vector_type(8))) __bf16 bf16x8;
typedef unsigned short u16;

#define GAS(p) ((const __attribute__((address_space(1))) void*)(p))
#define LAS(p) ((__attribute__((address_space(3))) void*)(p))

__device__ __forceinline__ u16 f32_to_bf16(float f) {
  unsigned u = __builtin_bit_cast(unsigned, f);
  u += 0x7FFFu + ((u >> 16) & 1u);
  return (u16)(u >> 16);
}

// ---------------- elementwise f32 -> bf16 ----------------
__global__ __launch_bounds__(256) void k_convert(const float* __restrict__ X,
                                                 u16* __restrict__ Y, int n4) {
  int i = blockIdx.x * 256 + threadIdx.x;
  if (i >= n4) return;
  float4 v = ((const float4*)X)[i];
  ushort4 r;
  r.x = f32_to_bf16(v.x); r.y = f32_to_bf16(v.y);
  r.z = f32_to_bf16(v.z); r.w = f32_to_bf16(v.w);
  ((ushort4*)Y)[i] = r;
}

// ---------------- W [K][N] f32 -> WT [N][K] bf16 ----------------
__global__ __launch_bounds__(256) void k_transpose_w(const float* __restrict__ W,
                                                     u16* __restrict__ WT,
                                                     int K, int N) {
  __shared__ float tile[32][33];
  int n0 = blockIdx.x * 32, k0 = blockIdx.y * 32;
  int tx = threadIdx.x & 31, ty = threadIdx.x >> 5;
#pragma unroll
  for (int r = 0; r < 4; ++r)
    tile[ty + r * 8][tx] = W[(long)(k0 + ty + r * 8) * N + n0 + tx];
  __syncthreads();
#pragma unroll
  for (int r = 0; r < 4; ++r)
    WT[(long)(n0 + ty + r * 8) * K + k0 + tx] = f32_to_bf16(tile[tx][ty + r * 8]);
}

// ---------------- V [BH][S][128] bf16 -> VT [BH][128][S] bf16 ----------------
__global__ __launch_bounds__(256) void k_transpose_v(const u16* __restrict__ V,
                                                     u16* __restrict__ VT) {
  __shared__ u16 tile[32][34];
  int s0 = blockIdx.x * 32, d0 = blockIdx.y * 32, bh = blockIdx.z;
  int tx = threadIdx.x & 31, ty = threadIdx.x >> 5;
  const u16* Vb = V + (long)bh * 2048 * 128;
  u16* VTb = VT + (long)bh * 128 * 2048;
#pragma unroll
  for (int r = 0; r < 4; ++r)
    tile[ty + r * 8][tx] = Vb[(long)(s0 + ty + r * 8) * 128 + d0 + tx];
  __syncthreads();
#pragma unroll
  for (int r = 0; r < 4; ++r)
    VTb[(long)(d0 + ty + r * 8) * 2048 + s0 + tx] = tile[tx][ty + r * 8];
}

// ---------------- m97-structure bf16 GEMM, 128x128 tile, BK=32 ----------------
template <int EPI>
__global__ __launch_bounds__(256) void k_gemm(
    const u16* __restrict__ A, const u16* __restrict__ BT,
    const float* __restrict__ bias,
    u16* __restrict__ Qo, u16* __restrict__ Ko, u16* __restrict__ Vo,
    float* __restrict__ Cout, int M, int N, int K) {
  __shared__ alignas(16) u16 As[128 * 32];
  __shared__ alignas(16) u16 Bs[128 * 32];
  const int t = threadIdx.x;
  const int wave = t >> 6, lane = t & 63;
  const int wr = wave >> 1, wc = wave & 1;
  const int l15 = lane & 15, l4 = lane >> 4;
  const int brow = blockIdx.x * 128, bcol = blockIdx.y * 128;

  const f32x4 fzero = {0.f, 0.f, 0.f, 0.f};
  f32x4 acc[4][4];
#pragma unroll
  for (int m = 0; m < 4; ++m)
#pragma unroll
    for (int n = 0; n < 4; ++n) acc[m][n] = fzero;

  const int c0 = wave * 64 + lane;
  const int c1 = 256 + c0;
  const u16* ga0 = A + (long)(brow + (c0 >> 2)) * K + (c0 & 3) * 8;
  const u16* ga1 = A + (long)(brow + (c1 >> 2)) * K + (c1 & 3) * 8;
  const u16* gb0 = BT + (long)(bcol + (c0 >> 2)) * K + (c0 & 3) * 8;
  const u16* gb1 = BT + (long)(bcol + (c1 >> 2)) * K + (c1 & 3) * 8;
  char* lA0 = (char*)As + (wave * 64) * 16;
  char* lA1 = (char*)As + (256 + wave * 64) * 16;
  char* lB0 = (char*)Bs + (wave * 64) * 16;
  char* lB1 = (char*)Bs + (256 + wave * 64) * 16;

  for (int k0 = 0; k0 < K; k0 += 32) {
    __builtin_amdgcn_global_load_lds(GAS(ga0 + k0), LAS(lA0), 16, 0, 0);
    __builtin_amdgcn_global_load_lds(GAS(ga1 + k0), LAS(lA1), 16, 0, 0);
    __builtin_amdgcn_global_load_lds(GAS(gb0 + k0), LAS(lB0), 16, 0, 0);
    __builtin_amdgcn_global_load_lds(GAS(gb1 + k0), LAS(lB1), 16, 0, 0);
    __syncthreads();
    bf16x8 af[4], bf[4];
#pragma unroll
    for (int m = 0; m < 4; ++m)
      af[m] = *(const bf16x8*)(As + (wr * 64 + m * 16 + l15) * 32 + l4 * 8);
#pragma unroll
    for (int n = 0; n < 4; ++n)
      bf[n] = *(const bf16x8*)(Bs + (wc * 64 + n * 16 + l15) * 32 + l4 * 8);
#pragma unroll
    for (int m = 0; m < 4; ++m)
#pragma unroll
      for (int n = 0; n < 4; ++n)
        acc[m][n] =
            __builtin_amdgcn_mfma_f32_16x16x32_bf16(af[m], bf[n], acc[m][n], 0, 0, 0);
    __syncthreads();
  }

  if (EPI == 0) {
    const int which = bcol >> 11;
    u16* dst = (which == 0) ? Qo : (which == 1) ? Ko : Vo;
    const int cbase = bcol & 2047;
#pragma unroll
    for (int n = 0; n < 4; ++n) {
      int col = cbase + wc * 64 + n * 16 + l15;
      int h = col >> 7, d = col & 127;
      float bv = bias[bcol + wc * 64 + n * 16 + l15];
#pragma unroll
      for (int m = 0; m < 4; ++m) {
#pragma unroll
        for (int r = 0; r < 4; ++r) {
          int row = brow + wr * 64 + m * 16 + l4 * 4 + r;
          int b = row >> 11, s = row & 2047;
          dst[(((long)(b * 16 + h)) * 2048 + s) * 128 + d] =
              f32_to_bf16(acc[m][n][r] + bv);
        }
      }
    }
  } else {
#pragma unroll
    for (int m = 0; m < 4; ++m) {
#pragma unroll
      for (int r = 0; r < 4; ++r) {
        int row = brow + wr * 64 + m * 16 + l4 * 4 + r;
#pragma unroll
        for (int n = 0; n < 4; ++n) {
          int col = bcol + wc * 64 + n * 16 + l15;
          Cout[(long)row * N + col] = acc[m][n][r] + bias[col];
        }
      }
    }
  }
}

// ---------------- flash attention with ALiBi, causal ----------------
// 1-wave blocks (64 threads), no barriers: each wave owns 16 q-rows.
// grid = 4096 blocks: b -> bh = b&31, qtile = 127 - (b>>5) (heavy-first LPT).
// Q,K [BH][S][128] bf16; VT [BH][128][S] bf16; Oa [B*S][2048] bf16.
__global__ __launch_bounds__(64, 2) void k_attn(const u16* __restrict__ Q,
                                                const u16* __restrict__ Kp,
                                                const u16* __restrict__ VT,
                                                u16* __restrict__ Oa) {
  __shared__ alignas(16) u16 Pl[2][16 * 64];  // double-buffered per-wave P
  const int bh = blockIdx.x & 31;
  const int qtile = 127 - ((int)blockIdx.x >> 5);
  const int b = bh >> 4, h = bh & 15;
  const int lane = threadIdx.x & 63;
  const int l15 = lane & 15, l4 = lane >> 4;
  const float LOG2E = 1.4426950408889634f;
  const float scale = 0.08838834764831845f * LOG2E;  // (1/sqrt(128))*log2e
  const float slope = exp2f(-0.5f * (float)h) * LOG2E;

  const int q0 = qtile * 16;
  const u16* Qb = Q + ((long)bh * 2048 + q0 + l15) * 128;
  bf16x8 qf[4];
#pragma unroll
  for (int kk = 0; kk < 4; ++kk) qf[kk] = *(const bf16x8*)(Qb + kk * 32 + l4 * 8);

  const u16* Kb = Kp + (long)bh * 2048 * 128;
  const u16* Vb = VT + (long)bh * 128 * 2048;

  float mrun[4], lrun[4];
  f32x4 O[8];
  const f32x4 fzero = {0.f, 0.f, 0.f, 0.f};
#pragma unroll
  for (int r = 0; r < 4; ++r) { mrun[r] = -1e30f; lrun[r] = 0.f; }
#pragma unroll
  for (int nb = 0; nb < 8; ++nb) O[nb] = fzero;

  const int irow = q0 + l4 * 4;  // this lane's 4 rows are irow+r
  const int jtmax = (q0 + 15) >> 6;
  for (int jt = 0; jt <= jtmax; ++jt) {
    const int j0 = jt * 64;
    u16* Pw = Pl[jt & 1];
    // ---- QK^T: S[16 q][64 j] in fp32 regs (bias folded, base-2 units) ----
    float sv[4][4];
#pragma unroll
    for (int cb = 0; cb < 4; ++cb) {
      f32x4 sa = fzero;
      const u16* kp = Kb + (long)(j0 + cb * 16 + l15) * 128 + l4 * 8;
#pragma unroll
      for (int kk = 0; kk < 4; ++kk) {
        bf16x8 kf = *(const bf16x8*)(kp + kk * 32);
        sa = __builtin_amdgcn_mfma_f32_16x16x32_bf16(qf[kk], kf, sa, 0, 0, 0);
      }
      const int j = j0 + cb * 16 + l15;
#pragma unroll
      for (int r = 0; r < 4; ++r) {
        int i = irow + r;
        float s = sa[r] * scale - slope * (float)(i - j);
        sv[cb][r] = (j <= i) ? s : -1e30f;
      }
    }
    // ---- online softmax (rows live in 16-lane groups sharing l4) ----
    float pm[4];
#pragma unroll
    for (int r = 0; r < 4; ++r) {
      float v = fmaxf(fmaxf(sv[0][r], sv[1][r]), fmaxf(sv[2][r], sv[3][r]));
      v = fmaxf(v, __shfl_xor(v, 1));
      v = fmaxf(v, __shfl_xor(v, 2));
      v = fmaxf(v, __shfl_xor(v, 4));
      v = fmaxf(v, __shfl_xor(v, 8));
      pm[r] = v;
    }
    float alpha[4], rs[4];
#pragma unroll
    for (int r = 0; r < 4; ++r) {
      float mnew = fmaxf(mrun[r], pm[r]);
      alpha[r] = exp2f(mrun[r] - mnew);
      mrun[r] = mnew;
      rs[r] = 0.f;
    }
    // ---- P = 2^(S-m), bf16 into XOR-swizzled per-wave LDS ----
#pragma unroll
    for (int cb = 0; cb < 4; ++cb) {
#pragma unroll
      for (int r = 0; r < 4; ++r) {
        float p = exp2f(sv[cb][r] - mrun[r]);
        rs[r] += p;
        int rloc = l4 * 4 + r;
        int cbyte = (cb * 16 + l15) * 2;
        *(u16*)((char*)Pw + rloc * 128 + (cbyte ^ ((rloc & 7) << 4))) =
            f32_to_bf16(p);
      }
    }
#pragma unroll
    for (int r = 0; r < 4; ++r) {
      float v = rs[r];
      v += __shfl_xor(v, 1);
      v += __shfl_xor(v, 2);
      v += __shfl_xor(v, 4);
      v += __shfl_xor(v, 8);
      lrun[r] = lrun[r] * alpha[r] + v;
    }
    // ---- read P as A-fragments (same-wave RAW; compiler waits lgkmcnt) ----
    bf16x8 pf0 = *(const bf16x8*)((char*)Pw + l15 * 128 +
                                  ((l4 * 16) ^ ((l15 & 7) << 4)));
    bf16x8 pf1 = *(const bf16x8*)((char*)Pw + l15 * 128 +
                                  ((64 + l4 * 16) ^ ((l15 & 7) << 4)));
#pragma unroll
    for (int nb = 0; nb < 8; ++nb)
#pragma unroll
      for (int r = 0; r < 4; ++r) O[nb][r] *= alpha[r];
    // ---- PV: V^T fragments straight from global (L2-resident) ----
#pragma unroll
    for (int nb = 0; nb < 8; ++nb) {
      const u16* vp = Vb + (long)(nb * 16 + l15) * 2048 + j0 + l4 * 8;
      bf16x8 v0 = *(const bf16x8*)(vp);
      bf16x8 v1 = *(const bf16x8*)(vp + 32);
      O[nb] = __builtin_amdgcn_mfma_f32_16x16x32_bf16(pf0, v0, O[nb], 0, 0, 0);
      O[nb] = __builtin_amdgcn_mfma_f32_16x16x32_bf16(pf1, v1, O[nb], 0, 0, 0);
    }
  }
#pragma unroll
  for (int r = 0; r < 4; ++r) {
    float inv = 1.f / lrun[r];
    int i = irow + r;
    u16* op = Oa + ((long)b * 2048 + i) * 2048 + h * 128;
#pragma unroll
    for (int nb = 0; nb < 8; ++nb) op[nb * 16 + l15] = f32_to_bf16(O[nb][r] * inv);
  }
}

extern "C" void kernel_launch(void* const* d_in, const int* in_sizes, int n_in,
                              void* d_out, int out_size, void* d_ws, size_t ws_size,
                              hipStream_t stream) {
  const float* x = (const float*)d_in[0];
  const float* Wqkv = (const float*)d_in[1];
  const float* bqkv = (const float*)d_in[2];
  const float* Wo = (const float*)d_in[3];
  const float* bo = (const float*)d_in[4];
  float* out = (float*)d_out;

  char* ws = (char*)d_ws;
  u16* xb = (u16*)(ws);
  u16* VTb = (u16*)(ws);  // aliases xb (xb dead after GEMM1)
  u16* WqkvT = (u16*)(ws + 16777216);
  u16* attn_out = (u16*)(ws + 16777216);  // aliases WqkvT (dead after GEMM1)
  u16* WoT = (u16*)(ws + 16777216 + 25165824);
  u16* Qb = (u16*)(ws + 50331648);
  u16* Kb = (u16*)(ws + 67108864);
  u16* Vb = (u16*)(ws + 83886080);

  k_convert<<<8192, 256, 0, stream>>>(x, xb, 8388608 / 4);
  k_transpose_w<<<dim3(192, 64), 256, 0, stream>>>(Wqkv, WqkvT, 2048, 6144);
  k_transpose_w<<<dim3(64, 64), 256, 0, stream>>>(Wo, WoT, 2048, 2048);
  k_gemm<0><<<dim3(32, 48), 256, 0, stream>>>(xb, WqkvT, bqkv, Qb, Kb, Vb,
                                              nullptr, 4096, 6144, 2048);
  k_transpose_v<<<dim3(64, 4, 32), 256, 0, stream>>>(Vb, VTb);
  k_attn<<<dim3(4096), 64, 0, stream>>>(Qb, Kb, VTb, attn_out);
  k_gemm<1><<<dim3(32, 16), 256, 0, stream>>>(attn_out, WoT, bo, nullptr,
                                              nullptr, nullptr, out, 4096, 2048,
                                              2048);
}